// Round 13
// baseline (584.512 us; speedup 1.0000x reference)
//
#include <hip/hip_runtime.h>
#include <stdint.h>

static constexpr int B  = 32;
static constexpr int T  = 350;
static constexpr int NIN = 2048;
static constexpr int NH  = 512;
static constexpr int NO  = 10;
static constexpr int BT  = B * T;

static constexpr float THETA = 10.0f;
static constexpr float BETA  = 0.36787944117144233f;   // e^-1 (refractory decay)
static constexpr float CREF  = 54.365636569180904707f; // SCALE_REF*THETA*e = 20e

// Workspace layout (bytes).
// W1Ts: slice-major [64 slices][2049 n][8 m] f32 (row 2048 = zeros)
static constexpr size_t OFF_W1TS = 0;                   // 4,196,352
static constexpr size_t OFF_SRM  = 4196352;             // 192 f32 (1 KB slot)
static constexpr size_t OFF_Z1   = 4197376;             // BT*512 f32 = 22,937,600
static constexpr size_t OFF_A1   = 27134976;            // BT*512 f32 -> ends 50,072,576
static constexpr size_t OFF_LST  = OFF_A1;              // BT*192 u16 (dead before fir1 writes a1)
static constexpr size_t OFF_CNT  = OFF_A1 + 4300800;    // BT*4

static constexpr int SLICE_F = 8;                        // floats per slice
static constexpr int NSLICE  = NH / SLICE_F;             // 64
static constexpr int SLICE_STRIDE = 2049 * SLICE_F;      // 16392 floats

// ============ k_prep: fused pack+transpose+decode (blocks 0..191),
// W1 -> slice-major W1Ts (192..1215), srm table + zero row (1216).
__global__ void __launch_bounds__(256) k_prep(const float* __restrict__ x,
                                              const float* __restrict__ W1,
                                              float* __restrict__ W1Ts,
                                              uint16_t* __restrict__ glst,
                                              int* __restrict__ gcnt,
                                              float* __restrict__ srm28) {
    int bid = blockIdx.x;
    if (bid < 192) {
        // block = (b, t-chunk of 64). Phase A: ballot words mw[n] (bits = t_local).
        // Phase B: 64x64 bit transpose per nblk group -> arr[t_local][nblk].
        // Phase C: decode 64 t's into glst/gcnt (mask never hits global).
        __shared__ uint64_t mw[2048];            // 16 KB
        __shared__ uint64_t arr[64][33];         // 16.9 KB (+1 pad: 2-way-free banks)
        __shared__ uint16_t lstb[4][200];        // per-wave decode scratch
        int b = bid / 6, tc = bid % 6;
        int wv = threadIdx.x >> 6, lane = threadIdx.x & 63;
        int tbase = tc * 64;
        int t_l = tbase + lane;
        // Phase A: 512 n per wave, 16-deep load batches (short latency chain)
        for (int g = 0; g < 32; ++g) {
            int n0 = wv * 512 + g * 16;
            float v[16];
            #pragma unroll
            for (int i = 0; i < 16; ++i) {
                const float* xp = x + ((size_t)b * NIN + n0 + i) * T;
                v[i] = (t_l < T) ? xp[t_l] : 0.f;
            }
            #pragma unroll
            for (int i = 0; i < 16; ++i) {
                uint64_t mk = __ballot(v[i] != 0.0f);
                if (lane == 0) mw[n0 + i] = mk;
            }
        }
        __syncthreads();
        // Phase B: transpose (8 nblk groups per wave)
        static const uint64_t AM[6] = {
            0x00000000FFFFFFFFull, 0x0000FFFF0000FFFFull, 0x00FF00FF00FF00FFull,
            0x0F0F0F0F0F0F0F0Full, 0x3333333333333333ull, 0x5555555555555555ull };
        for (int g = wv; g < 32; g += 4) {
            uint64_t w = mw[g * 64 + lane];      // lane = n_local, bits = t_local
            #pragma unroll
            for (int i = 0; i < 6; ++i) {
                int s = 32 >> i;
                uint64_t A = AM[i];
                uint64_t y = __shfl_xor((unsigned long long)w, s);
                if ((lane & s) == 0) w = (w & A)  | ((y & A) << s);
                else                 w = (w & ~A) | ((y & ~A) >> s);
            }
            arr[lane][g] = w;                    // lane = t_local, bits = n_local
        }
        __syncthreads();
        // Phase C: decode; wave wv handles t_local = wv*16 + r
        for (int r = 0; r < 16; ++r) {
            int tl = wv * 16 + r;
            int t = tbase + tl;
            if (t >= T) continue;                // wave-uniform
            int row = b * T + t;
            uint64_t w = (lane < 32) ? arr[tl][lane] : 0ull;
            int cnt = __popcll(w);
            int pre = cnt;
            #pragma unroll
            for (int off = 1; off < 64; off <<= 1) {
                int v = __shfl_up(pre, off);
                if (lane >= off) pre += v;
            }
            int total = __shfl(pre, 63);
            int excl = pre - cnt;
            uint16_t* lst = lstb[wv];
            while (w) {
                int bit = __builtin_ctzll(w);
                w &= w - 1;
                lst[excl++] = (uint16_t)((lane << 6) + bit);
            }
            int padded = (total + 7) & ~7;
            if (lane < padded - total) lst[total + lane] = 2048;  // zero row pad
            uint16_t* op = glst + (size_t)row * 192;
            for (int i = lane; i < padded; i += 64) op[i] = lst[i];
            if (lane == 0) gcnt[row] = padded;
        }
    } else if (bid < 1216) {
        __shared__ float tile[32][33];
        int idx = bid - 192;
        int n0 = (idx & 63) * 32, m0 = (idx >> 6) * 32;
        int tx = threadIdx.x & 31, ty0 = threadIdx.x >> 5;
        #pragma unroll
        for (int i = 0; i < 4; ++i) {
            int ty = ty0 + 8 * i;
            tile[ty][tx] = W1[(size_t)(m0 + ty) * NIN + n0 + tx];
        }
        __syncthreads();
        #pragma unroll
        for (int i = 0; i < 4; ++i) {
            int ty = ty0 + 8 * i;
            int n = n0 + ty, m = m0 + tx;
            W1Ts[(size_t)(m >> 3) * SLICE_STRIDE + n * SLICE_F + (m & 7)] = tile[tx][ty];
        }
    } else {
        int j = threadIdx.x;
        if (j < 192) {
            float v = 0.f;
            int i = j - 28;
            if (i >= 0 && i < 100) { float t = (float)i; v = (t * 0.1f) * expf(1.f - t * 0.1f); }
            srm28[j] = v;
        }
        for (int i = j; i < NSLICE * SLICE_F; i += 256)
            W1Ts[(size_t)(i >> 3) * SLICE_STRIDE + 2048 * SLICE_F + (i & 7)] = 0.f;
    }
}

// ============ k_z1s: LDS-staged gather (R10-proven form, 512 blocks, 2/CU).
// block = (slice s of 8 m, row-chunk of 1400). Stage 64 KB slice; 2 threads/row,
// 8 independent ds_read_b128 in flight, wave-uniform bounds. Ascending-n order.
__global__ void __launch_bounds__(256) k_z1s(const uint16_t* __restrict__ glst,
                                             const int* __restrict__ gcnt,
                                             const float* __restrict__ W1Ts,
                                             float* __restrict__ z1) {
    __shared__ float w1s[SLICE_STRIDE];     // 65,568 B -> 2 blocks/CU
    int s = blockIdx.x;                     // 0..63
    int bt0 = blockIdx.y * (BT / 8);        // 1400 rows per block
    const float4* src = (const float4*)(W1Ts + (size_t)s * SLICE_STRIDE);
    for (int i = threadIdx.x; i < SLICE_STRIDE / 4; i += 256)
        ((float4*)w1s)[i] = src[i];
    __syncthreads();

    int q  = threadIdx.x & 1;               // float4 within 8m
    int rl = threadIdx.x >> 1;              // 0..127 row slot
    for (int rr = rl; rr < BT / 8; rr += 128) {
        int row = bt0 + rr;
        int padded = gcnt[row];
        const ushort4* lp = (const ushort4*)(glst + (size_t)row * 192);
        float4 acc = {0, 0, 0, 0};
        for (int k = 0; k < padded; k += 8) {
            ushort4 q0 = lp[k >> 2];
            ushort4 q1 = lp[(k >> 2) + 1];
            const float* base = w1s + q * 4;
            float4 x0 = *(const float4*)(base + q0.x * SLICE_F);
            float4 x1 = *(const float4*)(base + q0.y * SLICE_F);
            float4 x2 = *(const float4*)(base + q0.z * SLICE_F);
            float4 x3 = *(const float4*)(base + q0.w * SLICE_F);
            float4 x4 = *(const float4*)(base + q1.x * SLICE_F);
            float4 x5 = *(const float4*)(base + q1.y * SLICE_F);
            float4 x6 = *(const float4*)(base + q1.z * SLICE_F);
            float4 x7 = *(const float4*)(base + q1.w * SLICE_F);
            acc.x += x0.x; acc.y += x0.y; acc.z += x0.z; acc.w += x0.w;
            acc.x += x1.x; acc.y += x1.y; acc.z += x1.z; acc.w += x1.w;
            acc.x += x2.x; acc.y += x2.y; acc.z += x2.z; acc.w += x2.w;
            acc.x += x3.x; acc.y += x3.y; acc.z += x3.z; acc.w += x3.w;
            acc.x += x4.x; acc.y += x4.y; acc.z += x4.z; acc.w += x4.w;
            acc.x += x5.x; acc.y += x5.y; acc.z += x5.z; acc.w += x5.w;
            acc.x += x6.x; acc.y += x6.y; acc.z += x6.z; acc.w += x6.w;
            acc.x += x7.x; acc.y += x7.y; acc.z += x7.z; acc.w += x7.w;
        }
        *(float4*)(z1 + (size_t)row * NH + s * SLICE_F + q * 4) = acc;
    }
}

// ============ k_fir1: causal FIR K=100, M=512 (R4-exact)
__global__ void __launch_bounds__(64) k_fir1(const float* __restrict__ src,
                                             float* __restrict__ dst,
                                             const float* __restrict__ srm28) {
    __shared__ float tb[192];
    int b = blockIdx.x, half = blockIdx.y, tg = blockIdx.z;
    int lane = threadIdx.x;
    for (int i = lane; i < 192; i += 64) tb[i] = srm28[i];
    __syncthreads();
    int t0 = tg * 16;
    int m = half * 256 + lane * 4;
    const float* sp = src + (size_t)b * T * NH + m;

    float4 acc[16];
    #pragma unroll
    for (int r = 0; r < 16; ++r) acc[r] = make_float4(0.f, 0.f, 0.f, 0.f);
    float c[16];
    #pragma unroll
    for (int r = 0; r < 16; ++r) c[r] = tb[r + 127];

    for (int o = 0; o < 8; ++o) {
        #pragma unroll
        for (int j = 0; j < 16; ++j) {
            int dd = o * 16 + j;
            int tau = t0 - 99 + dd;
            float4 v = make_float4(0.f, 0.f, 0.f, 0.f);
            if (tau >= 0 && tau < T) v = *(const float4*)(sp + (size_t)tau * NH);
            #pragma unroll
            for (int r = 0; r < 16; ++r) {
                acc[r].x += c[r] * v.x; acc[r].y += c[r] * v.y;
                acc[r].z += c[r] * v.z; acc[r].w += c[r] * v.w;
            }
            #pragma unroll
            for (int r = 15; r > 0; --r) c[r] = c[r - 1];
            int ci = 126 - dd;
            c[0] = tb[ci < 0 ? 0 : ci];
        }
    }
    #pragma unroll
    for (int r = 0; r < 16; ++r) {
        int t = t0 + r;
        if (t < T) *(float4*)(dst + ((size_t)b * T + t) * NH + m) = acc[r];
    }
}

// ============ k_l2: fused scan1 + z2 + fir2 + scan2 (block = one b, 512 thr).
// z2 lives only in LDS (zb); saves a node + the z2 global round-trip.
__global__ void __launch_bounds__(512) k_l2(const float* __restrict__ a1,
                                            const float* __restrict__ W2,
                                            const float* __restrict__ srm28,
                                            float* __restrict__ out) {
    __shared__ float w2s[NO * NH];        // 20 KB
    __shared__ uint64_t smask[16][8];
    __shared__ float tb[192];
    __shared__ float zb[350 * 11 + 16];   // z2 in stride-11 layout
    __shared__ float ab[352 * 10];
    constexpr int CT = 16;
    constexpr int NC = (T + CT - 1) / CT; // 22
    int b = blockIdx.x, tid = threadIdx.x;
    int wv = tid >> 6;
    for (int i = tid; i < NO * NH; i += 512) w2s[i] = W2[i];
    if (tid < 192) tb[tid] = srm28[tid];
    const float* up = a1 + (size_t)b * T * NH + tid;
    float A = 0.f, Bs = 0.f;
    float cur[CT], nxt[CT];
    #pragma unroll
    for (int j = 0; j < CT; ++j) cur[j] = up[(size_t)j * NH];
    __syncthreads();
    for (int c = 0; c < NC; ++c) {
        int t0 = c * CT;
        int nsteps = (T - t0 < CT) ? (T - t0) : CT;
        if (c + 1 < NC) {
            #pragma unroll
            for (int j = 0; j < CT; ++j) {
                int t = t0 + CT + j;
                nxt[j] = (t < T) ? up[(size_t)t * NH] : 0.f;
            }
        }
        #pragma unroll
        for (int j = 0; j < CT; ++j) {
            if (j < nsteps) {                 // nsteps uniform -> safe ballot
                float mem = cur[j] - CREF * Bs;
                float sp = (mem >= THETA) ? 1.0f : 0.0f;
                A = sp + BETA * A;
                Bs = BETA * (Bs + A);
                uint64_t mk = __ballot(sp != 0.0f);
                if ((tid & 63) == 0) smask[j][wv] = mk;
            }
        }
        __syncthreads();
        if (tid < nsteps * NO) {
            int j = tid / NO, o = tid - j * NO;
            const float* wrow = w2s + o * NH;
            float acc = 0.f;
            #pragma unroll
            for (int w8 = 0; w8 < 8; ++w8) {
                uint64_t mk = smask[j][w8];
                int base = w8 * 64;
                while (mk) {
                    int bit = __builtin_ctzll(mk);
                    mk &= mk - 1;
                    acc += wrow[base + bit];
                }
            }
            zb[(t0 + j) * 11 + o] = acc;      // LDS, not global
        }
        __syncthreads();
        #pragma unroll
        for (int j = 0; j < CT; ++j) cur[j] = nxt[j];
    }
    __syncthreads();
    // ---- fir2 over zb -> ab
    if (tid < 220) {
        int tt = tid / 10, o = tid - tt * 10;
        int t0 = tt * 16;
        float acc[16];
        #pragma unroll
        for (int r = 0; r < 16; ++r) acc[r] = 0.f;
        float c[16];
        #pragma unroll
        for (int r = 0; r < 16; ++r) c[r] = tb[r + 127];
        for (int oo = 0; oo < 8; ++oo) {
            #pragma unroll
            for (int j = 0; j < 16; ++j) {
                int dd = oo * 16 + j;
                int tau = t0 - 99 + dd;
                float v = (tau >= 0 && tau < T) ? zb[tau * 11 + o] : 0.f;
                #pragma unroll
                for (int r = 0; r < 16; ++r) acc[r] += c[r] * v;
                #pragma unroll
                for (int r = 15; r > 0; --r) c[r] = c[r - 1];
                int ci = 126 - dd;
                c[0] = tb[ci < 0 ? 0 : ci];
            }
        }
        #pragma unroll
        for (int r = 0; r < 16; ++r) {
            int t = t0 + r;
            if (t < T) ab[t * 10 + o] = acc[r];
        }
    }
    __syncthreads();
    // ---- final refractory scan -> out [B][NO][T]
    if (tid < NO) {
        int o = tid;
        float A2 = 0.f, B2 = 0.f;
        float* op = out + ((size_t)b * NO + o) * T;
        for (int t = 0; t < T; ++t) {
            float mem = ab[t * 10 + o] - CREF * B2;
            float sp = (mem >= THETA) ? 1.0f : 0.0f;
            A2 = sp + BETA * A2;
            B2 = BETA * (B2 + A2);
            op[t] = sp;
        }
    }
}

extern "C" void kernel_launch(void* const* d_in, const int* in_sizes, int n_in,
                              void* d_out, int out_size, void* d_ws, size_t ws_size,
                              hipStream_t stream) {
    const float* x  = (const float*)d_in[0];
    const float* W1 = (const float*)d_in[1];
    const float* W2 = (const float*)d_in[2];
    char* ws = (char*)d_ws;
    float*    W1Ts = (float*)(ws + OFF_W1TS);
    float*    srm  = (float*)(ws + OFF_SRM);
    float*    z1   = (float*)(ws + OFF_Z1);
    float*    a1   = (float*)(ws + OFF_A1);
    uint16_t* glst = (uint16_t*)(ws + OFF_LST);   // overlays A1 (dead before fir1)
    int*      gcnt = (int*)(ws + OFF_CNT);
    float*    out  = (float*)d_out;

    hipLaunchKernelGGL(k_prep, dim3(1217),      dim3(256), 0, stream, x, W1, W1Ts, glst, gcnt, srm);
    hipLaunchKernelGGL(k_z1s,  dim3(NSLICE, 8), dim3(256), 0, stream, glst, gcnt, W1Ts, z1);
    hipLaunchKernelGGL(k_fir1, dim3(B, 2, 22),  dim3(64),  0, stream, z1, a1, srm);
    hipLaunchKernelGGL(k_l2,   dim3(B),         dim3(512), 0, stream, a1, W2, srm, out);
}

// Round 14
// 376.082 us; speedup vs baseline: 1.5542x; 1.5542x over previous
//
#include <hip/hip_runtime.h>
#include <stdint.h>

static constexpr int B  = 32;
static constexpr int T  = 350;
static constexpr int NIN = 2048;
static constexpr int NH  = 512;
static constexpr int NO  = 10;
static constexpr int BT  = B * T;

static constexpr float THETA = 10.0f;
static constexpr float BETA  = 0.36787944117144233f;   // e^-1 (refractory decay)
static constexpr float CREF  = 54.365636569180904707f; // SCALE_REF*THETA*e = 20e

// Workspace layout (bytes).
// W1Ts: slice-major [64 slices][2049 n][8 m] f32 (row 2048 = zeros)
static constexpr size_t OFF_W1TS = 0;                   // 4,196,352
static constexpr size_t OFF_MASK = 4196352;             // 32*32*352 u64 = 2,883,584
static constexpr size_t OFF_SRM  = 7080960;             // 192 f32 (1 KB slot)
static constexpr size_t OFF_Z1   = 7081984;             // BT*512 f32 = 22,937,600
static constexpr size_t OFF_A1   = 30019584;            // BT*512 f32 -> ends 52,957,184
static constexpr size_t OFF_LST  = OFF_A1;              // BT*192 u16 (dead before fir1 writes a1)
static constexpr size_t OFF_CNT  = OFF_A1 + 4300800;    // BT*4

static constexpr int SLICE_F = 8;                        // floats per slice
static constexpr int NSLICE  = NH / SLICE_F;             // 64
static constexpr int SLICE_STRIDE = 2049 * SLICE_F;      // 16392 floats

// ============ k_prep (R10-proven): pack (0..1023) + W1->slice-major (1024..2047)
// + srm table / zero row (2048). Pack stores mask[b][nblk][t] t-contiguous.
__global__ void __launch_bounds__(256) k_prep(const float* __restrict__ x,
                                              const float* __restrict__ W1,
                                              float* __restrict__ W1Ts,
                                              uint64_t* __restrict__ mask,
                                              float* __restrict__ srm28) {
    int bid = blockIdx.x;
    if (bid < 1024) {
        __shared__ uint64_t tb[6][64];
        int b = bid >> 5, nblk = bid & 31;
        int wv = threadIdx.x >> 6, lane = threadIdx.x & 63;
        for (int g = 0; g < 4; ++g) {
            float v[4][6];
            #pragma unroll
            for (int i = 0; i < 4; ++i) {
                int nr = wv + 4 * (4 * g + i);
                const float* xp = x + ((size_t)b * NIN + nblk * 64 + nr) * T;
                #pragma unroll
                for (int c = 0; c < 6; ++c) {
                    int t = c * 64 + lane;
                    v[i][c] = (t < T) ? xp[t] : 0.f;
                }
            }
            #pragma unroll
            for (int i = 0; i < 4; ++i) {
                int nr = wv + 4 * (4 * g + i);
                #pragma unroll
                for (int c = 0; c < 6; ++c) {
                    uint64_t mk = __ballot(v[i][c] != 0.0f);
                    if (lane == 0) tb[c][nr] = mk;
                }
            }
        }
        __syncthreads();
        static const uint64_t AM[6] = {
            0x00000000FFFFFFFFull, 0x0000FFFF0000FFFFull, 0x00FF00FF00FF00FFull,
            0x0F0F0F0F0F0F0F0Full, 0x3333333333333333ull, 0x5555555555555555ull };
        for (int c = wv; c < 6; c += 4) {
            uint64_t w = tb[c][lane];            // lane = n, bits = t
            #pragma unroll
            for (int i = 0; i < 6; ++i) {
                int s = 32 >> i;
                uint64_t A = AM[i];
                uint64_t y = __shfl_xor((unsigned long long)w, s);
                if ((lane & s) == 0) w = (w & A)  | ((y & A) << s);
                else                 w = (w & ~A) | ((y & ~A) >> s);
            }
            int t = c * 64 + lane;               // lane = t, bits = n
            if (t < T) mask[((size_t)b * 32 + nblk) * 352 + t] = w;  // coalesced
        }
    } else if (bid < 2048) {
        __shared__ float tile[32][33];
        int idx = bid - 1024;
        int n0 = (idx & 63) * 32, m0 = (idx >> 6) * 32;
        int tx = threadIdx.x & 31, ty0 = threadIdx.x >> 5;
        #pragma unroll
        for (int i = 0; i < 4; ++i) {
            int ty = ty0 + 8 * i;
            tile[ty][tx] = W1[(size_t)(m0 + ty) * NIN + n0 + tx];
        }
        __syncthreads();
        #pragma unroll
        for (int i = 0; i < 4; ++i) {
            int ty = ty0 + 8 * i;
            int n = n0 + ty, m = m0 + tx;
            W1Ts[(size_t)(m >> 3) * SLICE_STRIDE + n * SLICE_F + (m & 7)] = tile[tx][ty];
        }
    } else {
        int j = threadIdx.x;
        if (j < 192) {
            float v = 0.f;
            int i = j - 28;
            if (i >= 0 && i < 100) { float t = (float)i; v = (t * 0.1f) * expf(1.f - t * 0.1f); }
            srm28[j] = v;
        }
        for (int i = j; i < NSLICE * SLICE_F; i += 256)
            W1Ts[(size_t)(i >> 3) * SLICE_STRIDE + 2048 * SLICE_F + (i & 7)] = 0.f;
    }
}

// ============ k_decode (R10-proven): mask -> per-(b,t) ascending index list,
// padded x8 with zero-row 2048, plus padded count. One wave per (b,t).
__global__ void __launch_bounds__(64) k_decode(const uint64_t* __restrict__ mask,
                                               uint16_t* __restrict__ glst,
                                               int* __restrict__ gcnt) {
    __shared__ uint16_t lst[192];
    int t = blockIdx.x, b = blockIdx.y;
    int row = b * T + t;
    int lane = threadIdx.x;
    uint64_t w = (lane < 32) ? mask[((size_t)b * 32 + lane) * 352 + t] : 0ull;
    int cnt = __popcll(w);
    int pre = cnt;
    #pragma unroll
    for (int off = 1; off < 64; off <<= 1) {
        int v = __shfl_up(pre, off);
        if (lane >= off) pre += v;
    }
    int total = __shfl(pre, 63);
    int excl = pre - cnt;
    while (w) {
        int bit = __builtin_ctzll(w);
        w &= w - 1;
        lst[excl++] = (uint16_t)((lane << 6) + bit);
    }
    int padded = (total + 7) & ~7;
    if (lane < padded - total) lst[total + lane] = 2048;   // zero row pad
    __syncthreads();
    uint16_t* op = glst + (size_t)row * 192;
    for (int i = lane; i < padded; i += 64) op[i] = lst[i];
    if (lane == 0) gcnt[row] = padded;
}

// ============ k_z1s (R10-proven, 70 µs): LDS-staged gather.
// block = (slice s of 8 m, row-chunk of 1400). Stage 64 KB slice (2 blk/CU);
// 2 threads/row, 8 independent ds_read_b128 in flight, wave-uniform bounds.
// Ascending-n summation order.
__global__ void __launch_bounds__(256) k_z1s(const uint16_t* __restrict__ glst,
                                             const int* __restrict__ gcnt,
                                             const float* __restrict__ W1Ts,
                                             float* __restrict__ z1) {
    __shared__ float w1s[SLICE_STRIDE];     // 65,568 B -> 2 blocks/CU
    int s = blockIdx.x;                     // 0..63
    int bt0 = blockIdx.y * (BT / 8);        // 1400 rows per block
    const float4* src = (const float4*)(W1Ts + (size_t)s * SLICE_STRIDE);
    for (int i = threadIdx.x; i < SLICE_STRIDE / 4; i += 256)
        ((float4*)w1s)[i] = src[i];
    __syncthreads();

    int q  = threadIdx.x & 1;               // float4 within 8m
    int rl = threadIdx.x >> 1;              // 0..127 row slot
    for (int rr = rl; rr < BT / 8; rr += 128) {
        int row = bt0 + rr;
        int padded = gcnt[row];
        const ushort4* lp = (const ushort4*)(glst + (size_t)row * 192);
        float4 acc = {0, 0, 0, 0};
        for (int k = 0; k < padded; k += 8) {
            ushort4 q0 = lp[k >> 2];
            ushort4 q1 = lp[(k >> 2) + 1];
            const float* base = w1s + q * 4;
            float4 x0 = *(const float4*)(base + q0.x * SLICE_F);
            float4 x1 = *(const float4*)(base + q0.y * SLICE_F);
            float4 x2 = *(const float4*)(base + q0.z * SLICE_F);
            float4 x3 = *(const float4*)(base + q0.w * SLICE_F);
            float4 x4 = *(const float4*)(base + q1.x * SLICE_F);
            float4 x5 = *(const float4*)(base + q1.y * SLICE_F);
            float4 x6 = *(const float4*)(base + q1.z * SLICE_F);
            float4 x7 = *(const float4*)(base + q1.w * SLICE_F);
            acc.x += x0.x; acc.y += x0.y; acc.z += x0.z; acc.w += x0.w;
            acc.x += x1.x; acc.y += x1.y; acc.z += x1.z; acc.w += x1.w;
            acc.x += x2.x; acc.y += x2.y; acc.z += x2.z; acc.w += x2.w;
            acc.x += x3.x; acc.y += x3.y; acc.z += x3.z; acc.w += x3.w;
            acc.x += x4.x; acc.y += x4.y; acc.z += x4.z; acc.w += x4.w;
            acc.x += x5.x; acc.y += x5.y; acc.z += x5.z; acc.w += x5.w;
            acc.x += x6.x; acc.y += x6.y; acc.z += x6.z; acc.w += x6.w;
            acc.x += x7.x; acc.y += x7.y; acc.z += x7.z; acc.w += x7.w;
        }
        *(float4*)(z1 + (size_t)row * NH + s * SLICE_F + q * 4) = acc;
    }
}

// ============ k_fir1: causal FIR K=100, M=512 (R4-exact)
__global__ void __launch_bounds__(64) k_fir1(const float* __restrict__ src,
                                             float* __restrict__ dst,
                                             const float* __restrict__ srm28) {
    __shared__ float tb[192];
    int b = blockIdx.x, half = blockIdx.y, tg = blockIdx.z;
    int lane = threadIdx.x;
    for (int i = lane; i < 192; i += 64) tb[i] = srm28[i];
    __syncthreads();
    int t0 = tg * 16;
    int m = half * 256 + lane * 4;
    const float* sp = src + (size_t)b * T * NH + m;

    float4 acc[16];
    #pragma unroll
    for (int r = 0; r < 16; ++r) acc[r] = make_float4(0.f, 0.f, 0.f, 0.f);
    float c[16];
    #pragma unroll
    for (int r = 0; r < 16; ++r) c[r] = tb[r + 127];

    for (int o = 0; o < 8; ++o) {
        #pragma unroll
        for (int j = 0; j < 16; ++j) {
            int dd = o * 16 + j;
            int tau = t0 - 99 + dd;
            float4 v = make_float4(0.f, 0.f, 0.f, 0.f);
            if (tau >= 0 && tau < T) v = *(const float4*)(sp + (size_t)tau * NH);
            #pragma unroll
            for (int r = 0; r < 16; ++r) {
                acc[r].x += c[r] * v.x; acc[r].y += c[r] * v.y;
                acc[r].z += c[r] * v.z; acc[r].w += c[r] * v.w;
            }
            #pragma unroll
            for (int r = 15; r > 0; --r) c[r] = c[r - 1];
            int ci = 126 - dd;
            c[0] = tb[ci < 0 ? 0 : ci];
        }
    }
    #pragma unroll
    for (int r = 0; r < 16; ++r) {
        int t = t0 + r;
        if (t < T) *(float4*)(dst + ((size_t)b * T + t) * NH + m) = acc[r];
    }
}

// ============ k_l2 (R13-proven): fused scan1 + z2 + fir2 + scan2.
// block = one b, 512 threads; z2 lives only in LDS; parallelism preserved
// within every phase (this fusion is safe, unlike pack+decode).
__global__ void __launch_bounds__(512) k_l2(const float* __restrict__ a1,
                                            const float* __restrict__ W2,
                                            const float* __restrict__ srm28,
                                            float* __restrict__ out) {
    __shared__ float w2s[NO * NH];        // 20 KB
    __shared__ uint64_t smask[16][8];
    __shared__ float tb[192];
    __shared__ float zb[350 * 11 + 16];   // z2, stride-11 layout
    __shared__ float ab[352 * 10];
    constexpr int CT = 16;
    constexpr int NC = (T + CT - 1) / CT; // 22
    int b = blockIdx.x, tid = threadIdx.x;
    int wv = tid >> 6;
    for (int i = tid; i < NO * NH; i += 512) w2s[i] = W2[i];
    if (tid < 192) tb[tid] = srm28[tid];
    const float* up = a1 + (size_t)b * T * NH + tid;
    float A = 0.f, Bs = 0.f;
    float cur[CT], nxt[CT];
    #pragma unroll
    for (int j = 0; j < CT; ++j) cur[j] = up[(size_t)j * NH];
    __syncthreads();
    for (int c = 0; c < NC; ++c) {
        int t0 = c * CT;
        int nsteps = (T - t0 < CT) ? (T - t0) : CT;
        if (c + 1 < NC) {
            #pragma unroll
            for (int j = 0; j < CT; ++j) {
                int t = t0 + CT + j;
                nxt[j] = (t < T) ? up[(size_t)t * NH] : 0.f;
            }
        }
        #pragma unroll
        for (int j = 0; j < CT; ++j) {
            if (j < nsteps) {                 // nsteps uniform -> safe ballot
                float mem = cur[j] - CREF * Bs;
                float sp = (mem >= THETA) ? 1.0f : 0.0f;
                A = sp + BETA * A;
                Bs = BETA * (Bs + A);
                uint64_t mk = __ballot(sp != 0.0f);
                if ((tid & 63) == 0) smask[j][wv] = mk;
            }
        }
        __syncthreads();
        if (tid < nsteps * NO) {
            int j = tid / NO, o = tid - j * NO;
            const float* wrow = w2s + o * NH;
            float acc = 0.f;
            #pragma unroll
            for (int w8 = 0; w8 < 8; ++w8) {
                uint64_t mk = smask[j][w8];
                int base = w8 * 64;
                while (mk) {
                    int bit = __builtin_ctzll(mk);
                    mk &= mk - 1;
                    acc += wrow[base + bit];
                }
            }
            zb[(t0 + j) * 11 + o] = acc;      // LDS, not global
        }
        __syncthreads();
        #pragma unroll
        for (int j = 0; j < CT; ++j) cur[j] = nxt[j];
    }
    __syncthreads();
    // ---- fir2 over zb -> ab
    if (tid < 220) {
        int tt = tid / 10, o = tid - tt * 10;
        int t0 = tt * 16;
        float acc[16];
        #pragma unroll
        for (int r = 0; r < 16; ++r) acc[r] = 0.f;
        float c[16];
        #pragma unroll
        for (int r = 0; r < 16; ++r) c[r] = tb[r + 127];
        for (int oo = 0; oo < 8; ++oo) {
            #pragma unroll
            for (int j = 0; j < 16; ++j) {
                int dd = oo * 16 + j;
                int tau = t0 - 99 + dd;
                float v = (tau >= 0 && tau < T) ? zb[tau * 11 + o] : 0.f;
                #pragma unroll
                for (int r = 0; r < 16; ++r) acc[r] += c[r] * v;
                #pragma unroll
                for (int r = 15; r > 0; --r) c[r] = c[r - 1];
                int ci = 126 - dd;
                c[0] = tb[ci < 0 ? 0 : ci];
            }
        }
        #pragma unroll
        for (int r = 0; r < 16; ++r) {
            int t = t0 + r;
            if (t < T) ab[t * 10 + o] = acc[r];
        }
    }
    __syncthreads();
    // ---- final refractory scan -> out [B][NO][T]
    if (tid < NO) {
        int o = tid;
        float A2 = 0.f, B2 = 0.f;
        float* op = out + ((size_t)b * NO + o) * T;
        for (int t = 0; t < T; ++t) {
            float mem = ab[t * 10 + o] - CREF * B2;
            float sp = (mem >= THETA) ? 1.0f : 0.0f;
            A2 = sp + BETA * A2;
            B2 = BETA * (B2 + A2);
            op[t] = sp;
        }
    }
}

extern "C" void kernel_launch(void* const* d_in, const int* in_sizes, int n_in,
                              void* d_out, int out_size, void* d_ws, size_t ws_size,
                              hipStream_t stream) {
    const float* x  = (const float*)d_in[0];
    const float* W1 = (const float*)d_in[1];
    const float* W2 = (const float*)d_in[2];
    char* ws = (char*)d_ws;
    float*    W1Ts = (float*)(ws + OFF_W1TS);
    uint64_t* mask = (uint64_t*)(ws + OFF_MASK);
    float*    srm  = (float*)(ws + OFF_SRM);
    float*    z1   = (float*)(ws + OFF_Z1);
    float*    a1   = (float*)(ws + OFF_A1);
    uint16_t* glst = (uint16_t*)(ws + OFF_LST);   // overlays A1 (dead before fir1)
    int*      gcnt = (int*)(ws + OFF_CNT);
    float*    out  = (float*)d_out;

    hipLaunchKernelGGL(k_prep,   dim3(2049),      dim3(256), 0, stream, x, W1, W1Ts, mask, srm);
    hipLaunchKernelGGL(k_decode, dim3(T, B),      dim3(64),  0, stream, mask, glst, gcnt);
    hipLaunchKernelGGL(k_z1s,    dim3(NSLICE, 8), dim3(256), 0, stream, glst, gcnt, W1Ts, z1);
    hipLaunchKernelGGL(k_fir1,   dim3(B, 2, 22),  dim3(64),  0, stream, z1, a1, srm);
    hipLaunchKernelGGL(k_l2,     dim3(B),         dim3(512), 0, stream, a1, W2, srm, out);
}

// Round 15
// 297.959 us; speedup vs baseline: 1.9617x; 1.2622x over previous
//
#include <hip/hip_runtime.h>
#include <stdint.h>

static constexpr int B  = 32;
static constexpr int T  = 350;
static constexpr int NIN = 2048;
static constexpr int NH  = 512;
static constexpr int NO  = 10;
static constexpr int BT  = B * T;

static constexpr float THETA = 10.0f;
static constexpr float BETA  = 0.36787944117144233f;   // e^-1 (refractory decay)
static constexpr float CREF  = 54.365636569180904707f; // SCALE_REF*THETA*e = 20e

// Workspace layout (bytes).
// W1Ts: slice-major [64 slices][2049 n][8 m] f32 (row 2048 = zeros)
static constexpr size_t OFF_W1TS = 0;                   // 4,196,352
static constexpr size_t OFF_MASK = 4196352;             // 32*32*352 u64 = 2,883,584
static constexpr size_t OFF_SRM  = 7080960;             // 192 f32 (1 KB slot)
static constexpr size_t OFF_Z1   = 7081984;             // BT*512 f32 = 22,937,600
static constexpr size_t OFF_A1   = 30019584;            // BT*512 f32 -> ends 52,957,184
static constexpr size_t OFF_LST  = OFF_A1;              // BT*192 u16 (dead before fir1 writes a1)
static constexpr size_t OFF_CNT  = OFF_A1 + 4300800;    // BT*4
static constexpr size_t OFF_SMK  = 52957184;            // BT*8 u64 = 716,800 (layer-1 spike masks)

static constexpr int SLICE_F = 8;                        // floats per slice
static constexpr int NSLICE  = NH / SLICE_F;             // 64
static constexpr int SLICE_STRIDE = 2049 * SLICE_F;      // 16392 floats

// ============ k_prep (R10-proven): pack (0..1023) + W1->slice-major (1024..2047)
// + srm table / zero row (2048). Pack stores mask[b][nblk][t] t-contiguous.
__global__ void __launch_bounds__(256) k_prep(const float* __restrict__ x,
                                              const float* __restrict__ W1,
                                              float* __restrict__ W1Ts,
                                              uint64_t* __restrict__ mask,
                                              float* __restrict__ srm28) {
    int bid = blockIdx.x;
    if (bid < 1024) {
        __shared__ uint64_t tb[6][64];
        int b = bid >> 5, nblk = bid & 31;
        int wv = threadIdx.x >> 6, lane = threadIdx.x & 63;
        for (int g = 0; g < 4; ++g) {
            float v[4][6];
            #pragma unroll
            for (int i = 0; i < 4; ++i) {
                int nr = wv + 4 * (4 * g + i);
                const float* xp = x + ((size_t)b * NIN + nblk * 64 + nr) * T;
                #pragma unroll
                for (int c = 0; c < 6; ++c) {
                    int t = c * 64 + lane;
                    v[i][c] = (t < T) ? xp[t] : 0.f;
                }
            }
            #pragma unroll
            for (int i = 0; i < 4; ++i) {
                int nr = wv + 4 * (4 * g + i);
                #pragma unroll
                for (int c = 0; c < 6; ++c) {
                    uint64_t mk = __ballot(v[i][c] != 0.0f);
                    if (lane == 0) tb[c][nr] = mk;
                }
            }
        }
        __syncthreads();
        static const uint64_t AM[6] = {
            0x00000000FFFFFFFFull, 0x0000FFFF0000FFFFull, 0x00FF00FF00FF00FFull,
            0x0F0F0F0F0F0F0F0Full, 0x3333333333333333ull, 0x5555555555555555ull };
        for (int c = wv; c < 6; c += 4) {
            uint64_t w = tb[c][lane];            // lane = n, bits = t
            #pragma unroll
            for (int i = 0; i < 6; ++i) {
                int s = 32 >> i;
                uint64_t A = AM[i];
                uint64_t y = __shfl_xor((unsigned long long)w, s);
                if ((lane & s) == 0) w = (w & A)  | ((y & A) << s);
                else                 w = (w & ~A) | ((y & ~A) >> s);
            }
            int t = c * 64 + lane;               // lane = t, bits = n
            if (t < T) mask[((size_t)b * 32 + nblk) * 352 + t] = w;  // coalesced
        }
    } else if (bid < 2048) {
        __shared__ float tile[32][33];
        int idx = bid - 1024;
        int n0 = (idx & 63) * 32, m0 = (idx >> 6) * 32;
        int tx = threadIdx.x & 31, ty0 = threadIdx.x >> 5;
        #pragma unroll
        for (int i = 0; i < 4; ++i) {
            int ty = ty0 + 8 * i;
            tile[ty][tx] = W1[(size_t)(m0 + ty) * NIN + n0 + tx];
        }
        __syncthreads();
        #pragma unroll
        for (int i = 0; i < 4; ++i) {
            int ty = ty0 + 8 * i;
            int n = n0 + ty, m = m0 + tx;
            W1Ts[(size_t)(m >> 3) * SLICE_STRIDE + n * SLICE_F + (m & 7)] = tile[tx][ty];
        }
    } else {
        int j = threadIdx.x;
        if (j < 192) {
            float v = 0.f;
            int i = j - 28;
            if (i >= 0 && i < 100) { float t = (float)i; v = (t * 0.1f) * expf(1.f - t * 0.1f); }
            srm28[j] = v;
        }
        for (int i = j; i < NSLICE * SLICE_F; i += 256)
            W1Ts[(size_t)(i >> 3) * SLICE_STRIDE + 2048 * SLICE_F + (i & 7)] = 0.f;
    }
}

// ============ k_decode (R10-proven): mask -> per-(b,t) ascending index list,
// padded x8 with zero-row 2048, plus padded count. One wave per (b,t).
__global__ void __launch_bounds__(64) k_decode(const uint64_t* __restrict__ mask,
                                               uint16_t* __restrict__ glst,
                                               int* __restrict__ gcnt) {
    __shared__ uint16_t lst[192];
    int t = blockIdx.x, b = blockIdx.y;
    int row = b * T + t;
    int lane = threadIdx.x;
    uint64_t w = (lane < 32) ? mask[((size_t)b * 32 + lane) * 352 + t] : 0ull;
    int cnt = __popcll(w);
    int pre = cnt;
    #pragma unroll
    for (int off = 1; off < 64; off <<= 1) {
        int v = __shfl_up(pre, off);
        if (lane >= off) pre += v;
    }
    int total = __shfl(pre, 63);
    int excl = pre - cnt;
    while (w) {
        int bit = __builtin_ctzll(w);
        w &= w - 1;
        lst[excl++] = (uint16_t)((lane << 6) + bit);
    }
    int padded = (total + 7) & ~7;
    if (lane < padded - total) lst[total + lane] = 2048;   // zero row pad
    __syncthreads();
    uint16_t* op = glst + (size_t)row * 192;
    for (int i = lane; i < padded; i += 64) op[i] = lst[i];
    if (lane == 0) gcnt[row] = padded;
}

// ============ k_z1s (R10-proven, 70 µs): LDS-staged gather.
__global__ void __launch_bounds__(256) k_z1s(const uint16_t* __restrict__ glst,
                                             const int* __restrict__ gcnt,
                                             const float* __restrict__ W1Ts,
                                             float* __restrict__ z1) {
    __shared__ float w1s[SLICE_STRIDE];     // 65,568 B -> 2 blocks/CU
    int s = blockIdx.x;                     // 0..63
    int bt0 = blockIdx.y * (BT / 8);        // 1400 rows per block
    const float4* src = (const float4*)(W1Ts + (size_t)s * SLICE_STRIDE);
    for (int i = threadIdx.x; i < SLICE_STRIDE / 4; i += 256)
        ((float4*)w1s)[i] = src[i];
    __syncthreads();

    int q  = threadIdx.x & 1;               // float4 within 8m
    int rl = threadIdx.x >> 1;              // 0..127 row slot
    for (int rr = rl; rr < BT / 8; rr += 128) {
        int row = bt0 + rr;
        int padded = gcnt[row];
        const ushort4* lp = (const ushort4*)(glst + (size_t)row * 192);
        float4 acc = {0, 0, 0, 0};
        for (int k = 0; k < padded; k += 8) {
            ushort4 q0 = lp[k >> 2];
            ushort4 q1 = lp[(k >> 2) + 1];
            const float* base = w1s + q * 4;
            float4 x0 = *(const float4*)(base + q0.x * SLICE_F);
            float4 x1 = *(const float4*)(base + q0.y * SLICE_F);
            float4 x2 = *(const float4*)(base + q0.z * SLICE_F);
            float4 x3 = *(const float4*)(base + q0.w * SLICE_F);
            float4 x4 = *(const float4*)(base + q1.x * SLICE_F);
            float4 x5 = *(const float4*)(base + q1.y * SLICE_F);
            float4 x6 = *(const float4*)(base + q1.z * SLICE_F);
            float4 x7 = *(const float4*)(base + q1.w * SLICE_F);
            acc.x += x0.x; acc.y += x0.y; acc.z += x0.z; acc.w += x0.w;
            acc.x += x1.x; acc.y += x1.y; acc.z += x1.z; acc.w += x1.w;
            acc.x += x2.x; acc.y += x2.y; acc.z += x2.z; acc.w += x2.w;
            acc.x += x3.x; acc.y += x3.y; acc.z += x3.z; acc.w += x3.w;
            acc.x += x4.x; acc.y += x4.y; acc.z += x4.z; acc.w += x4.w;
            acc.x += x5.x; acc.y += x5.y; acc.z += x5.z; acc.w += x5.w;
            acc.x += x6.x; acc.y += x6.y; acc.z += x6.z; acc.w += x6.w;
            acc.x += x7.x; acc.y += x7.y; acc.z += x7.z; acc.w += x7.w;
        }
        *(float4*)(z1 + (size_t)row * NH + s * SLICE_F + q * 4) = acc;
    }
}

// ============ k_fir1: causal FIR K=100, M=512 (R4-exact)
__global__ void __launch_bounds__(64) k_fir1(const float* __restrict__ src,
                                             float* __restrict__ dst,
                                             const float* __restrict__ srm28) {
    __shared__ float tb[192];
    int b = blockIdx.x, half = blockIdx.y, tg = blockIdx.z;
    int lane = threadIdx.x;
    for (int i = lane; i < 192; i += 64) tb[i] = srm28[i];
    __syncthreads();
    int t0 = tg * 16;
    int m = half * 256 + lane * 4;
    const float* sp = src + (size_t)b * T * NH + m;

    float4 acc[16];
    #pragma unroll
    for (int r = 0; r < 16; ++r) acc[r] = make_float4(0.f, 0.f, 0.f, 0.f);
    float c[16];
    #pragma unroll
    for (int r = 0; r < 16; ++r) c[r] = tb[r + 127];

    for (int o = 0; o < 8; ++o) {
        #pragma unroll
        for (int j = 0; j < 16; ++j) {
            int dd = o * 16 + j;
            int tau = t0 - 99 + dd;
            float4 v = make_float4(0.f, 0.f, 0.f, 0.f);
            if (tau >= 0 && tau < T) v = *(const float4*)(sp + (size_t)tau * NH);
            #pragma unroll
            for (int r = 0; r < 16; ++r) {
                acc[r].x += c[r] * v.x; acc[r].y += c[r] * v.y;
                acc[r].z += c[r] * v.z; acc[r].w += c[r] * v.w;
            }
            #pragma unroll
            for (int r = 15; r > 0; --r) c[r] = c[r - 1];
            int ci = 126 - dd;
            c[0] = tb[ci < 0 ? 0 : ci];
        }
    }
    #pragma unroll
    for (int r = 0; r < 16; ++r) {
        int t = t0 + r;
        if (t < T) *(float4*)(dst + ((size_t)b * T + t) * NH + m) = acc[r];
    }
}

// ============ k_scan1: barrier-free layer-1 spike scan emitting MASKS.
// 256 blocks x 64 threads (one wave/block, 1 wave/CU, full-device spread).
// thread = (b,m); depth-2 chunk prefetch; per-step intra-wave ballot;
// lane 0 stores the wave's 64-m mask word. No __syncthreads anywhere.
__global__ void __launch_bounds__(64) k_scan1(const float* __restrict__ a1,
                                              uint64_t* __restrict__ smaskg) {
    constexpr int CT = 16;
    constexpr int NC = (T + CT - 1) / CT;   // 22
    int tid = blockIdx.x * 64 + threadIdx.x;
    int b = tid >> 9, m = tid & 511;
    int w8 = m >> 6;                        // wave-uniform (64-aligned m ranges)
    const float* up = a1 + (size_t)b * T * NH + m;
    float A = 0.f, Bs = 0.f;
    float c0[CT], c1[CT], c2[CT];
    #pragma unroll
    for (int j = 0; j < CT; ++j) c0[j] = up[(size_t)j * NH];
    #pragma unroll
    for (int j = 0; j < CT; ++j) {
        int t = CT + j;
        c1[j] = (t < T) ? up[(size_t)t * NH] : 0.f;
    }
    for (int c = 0; c < NC; ++c) {
        int t0 = c * CT;
        int nsteps = (T - t0 < CT) ? (T - t0) : CT;
        if (c + 2 < NC) {
            #pragma unroll
            for (int j = 0; j < CT; ++j) {
                int t = t0 + 2 * CT + j;
                c2[j] = (t < T) ? up[(size_t)t * NH] : 0.f;
            }
        }
        #pragma unroll
        for (int j = 0; j < CT; ++j) {
            if (j < nsteps) {                 // uniform -> safe ballot
                float mem = c0[j] - CREF * Bs;
                float sp = (mem >= THETA) ? 1.0f : 0.0f;
                A = sp + BETA * A;
                Bs = BETA * (Bs + A);
                uint64_t mk = __ballot(sp != 0.0f);
                if (threadIdx.x == 0) smaskg[((size_t)b * T + t0 + j) * 8 + w8] = mk;
            }
        }
        #pragma unroll
        for (int j = 0; j < CT; ++j) { c0[j] = c1[j]; c1[j] = c2[j]; }
    }
}

// ============ k_tail: z2 gather from masks + fir2 + scan2. block = one b.
// LDS: w2s (reused as ab after gather) + masks + srm + zb = 59.1 KB.
__global__ void __launch_bounds__(256) k_tail(const uint64_t* __restrict__ smaskg,
                                              const float* __restrict__ W2,
                                              const float* __restrict__ srm28,
                                              float* __restrict__ out) {
    __shared__ float w2s_ab[NO * NH];      // 20 KB: W2 during gather, ab after
    __shared__ uint64_t smk[T * 8];        // 22.4 KB
    __shared__ float tb[192];
    __shared__ float zb[350 * 11 + 16];    // 15.4 KB (stride 11)
    int b = blockIdx.x, tid = threadIdx.x;
    for (int i = tid; i < NO * NH; i += 256) w2s_ab[i] = W2[i];
    const uint64_t* mp = smaskg + (size_t)b * T * 8;
    for (int i = tid; i < T * 8; i += 256) smk[i] = mp[i];
    if (tid < 192) tb[tid] = srm28[tid];
    __syncthreads();
    // ---- z2 gather: ascending w8 / ascending bit = ascending m (bit-exact)
    for (int i = tid; i < T * NO; i += 256) {
        int t = i / NO, o = i - t * NO;
        const float* wrow = w2s_ab + o * NH;
        float acc = 0.f;
        #pragma unroll
        for (int w8 = 0; w8 < 8; ++w8) {
            uint64_t mk = smk[t * 8 + w8];
            int base = w8 * 64;
            while (mk) {
                int bit = __builtin_ctzll(mk);
                mk &= mk - 1;
                acc += wrow[base + bit];
            }
        }
        zb[t * 11 + o] = acc;
    }
    __syncthreads();
    // ---- fir2: zb -> ab (ab aliases w2s, dead after gather)
    float* ab = w2s_ab;
    if (tid < 220) {
        int tt = tid / 10, o = tid - tt * 10;
        int t0 = tt * 16;
        float acc[16];
        #pragma unroll
        for (int r = 0; r < 16; ++r) acc[r] = 0.f;
        float c[16];
        #pragma unroll
        for (int r = 0; r < 16; ++r) c[r] = tb[r + 127];
        for (int oo = 0; oo < 8; ++oo) {
            #pragma unroll
            for (int j = 0; j < 16; ++j) {
                int dd = oo * 16 + j;
                int tau = t0 - 99 + dd;
                float v = (tau >= 0 && tau < T) ? zb[tau * 11 + o] : 0.f;
                #pragma unroll
                for (int r = 0; r < 16; ++r) acc[r] += c[r] * v;
                #pragma unroll
                for (int r = 15; r > 0; --r) c[r] = c[r - 1];
                int ci = 126 - dd;
                c[0] = tb[ci < 0 ? 0 : ci];
            }
        }
        #pragma unroll
        for (int r = 0; r < 16; ++r) {
            int t = t0 + r;
            if (t < T) ab[t * 10 + o] = acc[r];
        }
    }
    __syncthreads();
    // ---- final refractory scan -> out [B][NO][T]
    if (tid < NO) {
        int o = tid;
        float A2 = 0.f, B2 = 0.f;
        float* op = out + ((size_t)b * NO + o) * T;
        for (int t = 0; t < T; ++t) {
            float mem = ab[t * 10 + o] - CREF * B2;
            float sp = (mem >= THETA) ? 1.0f : 0.0f;
            A2 = sp + BETA * A2;
            B2 = BETA * (B2 + A2);
            op[t] = sp;
        }
    }
}

extern "C" void kernel_launch(void* const* d_in, const int* in_sizes, int n_in,
                              void* d_out, int out_size, void* d_ws, size_t ws_size,
                              hipStream_t stream) {
    const float* x  = (const float*)d_in[0];
    const float* W1 = (const float*)d_in[1];
    const float* W2 = (const float*)d_in[2];
    char* ws = (char*)d_ws;
    float*    W1Ts   = (float*)(ws + OFF_W1TS);
    uint64_t* mask   = (uint64_t*)(ws + OFF_MASK);
    float*    srm    = (float*)(ws + OFF_SRM);
    float*    z1     = (float*)(ws + OFF_Z1);
    float*    a1     = (float*)(ws + OFF_A1);
    uint16_t* glst   = (uint16_t*)(ws + OFF_LST);   // overlays A1 (dead before fir1)
    int*      gcnt   = (int*)(ws + OFF_CNT);
    uint64_t* smaskg = (uint64_t*)(ws + OFF_SMK);
    float*    out    = (float*)d_out;

    hipLaunchKernelGGL(k_prep,   dim3(2049),      dim3(256), 0, stream, x, W1, W1Ts, mask, srm);
    hipLaunchKernelGGL(k_decode, dim3(T, B),      dim3(64),  0, stream, mask, glst, gcnt);
    hipLaunchKernelGGL(k_z1s,    dim3(NSLICE, 8), dim3(256), 0, stream, glst, gcnt, W1Ts, z1);
    hipLaunchKernelGGL(k_fir1,   dim3(B, 2, 22),  dim3(64),  0, stream, z1, a1, srm);
    hipLaunchKernelGGL(k_scan1,  dim3(256),       dim3(64),  0, stream, a1, smaskg);
    hipLaunchKernelGGL(k_tail,   dim3(B),         dim3(256), 0, stream, smaskg, W2, srm, out);
}